// Round 2
// baseline (988.297 us; speedup 1.0000x reference)
//
#include <hip/hip_runtime.h>
#include <math.h>

#define NN 8192
#define NE 262144
#define FIN 128
#define HC 256
#define CC 64
#define NCLS 8

// ---------------- ws layout (floats) ----------------
constexpr size_t OFF_XS    = 0;                              // N*256
constexpr size_t OFF_ASRC  = OFF_XS + (size_t)NN * 256;      // N*4
constexpr size_t OFF_ADST  = OFF_ASRC + (size_t)NN * 4;      // N*4
constexpr size_t OFF_ALPHA = OFF_ADST + (size_t)NN * 4;      // E*4
constexpr size_t OFF_CONF1 = OFF_ALPHA + (size_t)NE * 4;     // E
constexpr size_t OFF_CONF2 = OFF_CONF1 + (size_t)NE;         // E
constexpr size_t OFF_PROBE = OFF_CONF2 + (size_t)NE;         // E
constexpr size_t OFF_COEF1 = OFF_PROBE + (size_t)NE;         // E
constexpr size_t OFF_COEF2 = OFF_COEF1 + (size_t)NE;         // E
constexpr size_t OFF_H1    = OFF_COEF2 + (size_t)NE;         // N*256
constexpr size_t OFF_A     = OFF_H1 + (size_t)NN * 256;      // N*256
constexpr size_t OFF_B     = OFF_A + (size_t)NN * 256;       // N*256
constexpr size_t OFF_H2    = OFF_B + (size_t)NN * 256;       // N*64
constexpr size_t OFF_DINV  = OFF_H2 + (size_t)NN * 64;       // N
constexpr size_t OFF_SUMEA = OFF_DINV + (size_t)NN;          // 4 (3 used)
constexpr size_t OFF_M     = OFF_SUMEA + 4;                  // 12
constexpr size_t OFF_AELOOP= OFF_M + 12;                     // 4
constexpr size_t OFF_INT   = OFF_AELOOP + 4;                 // ints from here
// int sub-layout (relative to int* base at OFF_INT)
constexpr size_t IOFF_DEGC   = 0;                 // NN
constexpr size_t IOFF_DEGR   = IOFF_DEGC + NN;    // NN
constexpr size_t IOFF_COLOFF = IOFF_DEGR + NN;    // NN+1
constexpr size_t IOFF_CURSOR = IOFF_COLOFF + NN + 1; // NN
constexpr size_t IOFF_CSRROW = IOFF_CURSOR + NN;  // NE
constexpr size_t IOFF_CSREID = IOFF_CSRROW + NE;  // NE

// ---------------- helpers ----------------
__device__ __forceinline__ float wave_sum(float v) {
    for (int o = 32; o; o >>= 1) v += __shfl_xor(v, o);
    return v;
}
__device__ __forceinline__ float wave_max(float v) {
    for (int o = 32; o; o >>= 1) v = fmaxf(v, __shfl_xor(v, o));
    return v;
}
__device__ __forceinline__ float eluf(float v) { return v > 0.f ? v : (expf(v) - 1.f); }
__device__ __forceinline__ float sigmf(float v) { return 1.f / (1.f + expf(-v)); }

// ---------------- kernels ----------------
__global__ __launch_bounds__(256) void kz_small(int* deg_col, int* deg_row, float* sum_ea) {
    int i = blockIdx.x * blockDim.x + threadIdx.x;
    if (i < NN) { deg_col[i] = 0; deg_row[i] = 0; }
    if (i < 3) sum_ea[i] = 0.f;
}

// M[d*4+h] = sum_c lin_edge_w[d,h*64+c] * att_edge[h,c]
__global__ void k_M(const float* lew, const float* att_edge, float* M) {
    int t = threadIdx.x;
    if (t < 12) {
        int d = t >> 2, h = t & 3;
        float s = 0.f;
        for (int c = 0; c < 64; c++) s = fmaf(lew[d * 256 + h * 64 + c], att_edge[h * 64 + c], s);
        M[t] = s; // M[d*4+h], t = d*4+h
    }
}

// xs = x @ gat_lin_w ; a_src/a_dst per (node, head)
__global__ __launch_bounds__(256) void k_node(const float* __restrict__ x, const float* __restrict__ W,
                                              const float* __restrict__ att_src, const float* __restrict__ att_dst,
                                              float* __restrict__ xs, float* __restrict__ a_src, float* __restrict__ a_dst) {
    __shared__ float xl[FIN];
    int i = blockIdx.x, t = threadIdx.x;
    if (t < FIN) xl[t] = x[(size_t)i * FIN + t];
    __syncthreads();
    float acc = 0.f;
#pragma unroll 8
    for (int k = 0; k < FIN; k++) acc = fmaf(xl[k], W[k * 256 + t], acc);
    xs[(size_t)i * 256 + t] = acc;
    float ps = wave_sum(acc * att_src[t]);
    float pd = wave_sum(acc * att_dst[t]);
    if ((t & 63) == 0) { a_src[i * 4 + (t >> 6)] = ps; a_dst[i * 4 + (t >> 6)] = pd; }
}

__global__ __launch_bounds__(256) void k_edge(const int* __restrict__ ei, const float* __restrict__ eattr,
                                              const float* __restrict__ M,
                                              const float* __restrict__ a_src, const float* __restrict__ a_dst,
                                              const float* __restrict__ c1w, const float* __restrict__ c1b,
                                              const float* __restrict__ c2w, const float* __restrict__ c2b,
                                              float* __restrict__ alpha, float* __restrict__ conf1, float* __restrict__ conf2,
                                              int* __restrict__ deg_col, int* __restrict__ deg_row, float* __restrict__ sum_ea) {
    int e = blockIdx.x * 256 + threadIdx.x;
    int r = ei[e], c = ei[NE + e];
    float ea0 = eattr[e * 3 + 0], ea1 = eattr[e * 3 + 1], ea2 = eattr[e * 3 + 2];
#pragma unroll
    for (int h = 0; h < 4; h++) {
        float ae = fmaf(ea0, M[0 * 4 + h], fmaf(ea1, M[1 * 4 + h], ea2 * M[2 * 4 + h]));
        float v = a_src[r * 4 + h] + a_dst[c * 4 + h] + ae;
        alpha[(size_t)e * 4 + h] = v > 0.f ? v : 0.2f * v;
    }
    conf1[e] = sigmf(fmaf(ea0, c1w[0], fmaf(ea1, c1w[1], fmaf(ea2, c1w[2], c1b[0]))));
    conf2[e] = sigmf(fmaf(ea0, c2w[0], fmaf(ea1, c2w[1], fmaf(ea2, c2w[2], c2b[0]))));
    atomicAdd(&deg_col[c], 1);
    atomicAdd(&deg_row[r], 1);
    float s0 = wave_sum(ea0), s1 = wave_sum(ea1), s2 = wave_sum(ea2);
    if ((threadIdx.x & 63) == 0) {
        atomicAdd(&sum_ea[0], s0); atomicAdd(&sum_ea[1], s1); atomicAdd(&sum_ea[2], s2);
    }
}

__global__ void k_loop(const float* sum_ea, const float* M, float* aeloop) {
    int h = threadIdx.x;
    if (h < 4) {
        float m0 = sum_ea[0] * (1.f / NE), m1 = sum_ea[1] * (1.f / NE), m2 = sum_ea[2] * (1.f / NE);
        aeloop[h] = fmaf(m0, M[0 * 4 + h], fmaf(m1, M[1 * 4 + h], m2 * M[2 * 4 + h]));
    }
}

__global__ __launch_bounds__(256) void k_dinv(const int* deg_row, float* dinv) {
    int i = blockIdx.x * blockDim.x + threadIdx.x;
    if (i < NN) { int d = deg_row[i]; dinv[i] = d > 0 ? rsqrtf((float)d) : 0.f; }
}

__global__ __launch_bounds__(256) void k_scan(const int* __restrict__ deg_col, int* __restrict__ col_off, int* __restrict__ cursor) {
    __shared__ int sd[256];
    int t = threadIdx.x;
    int base_i = t * 32;
    int loc[32];
    int s = 0;
#pragma unroll
    for (int q = 0; q < 32; q++) { loc[q] = deg_col[base_i + q]; s += loc[q]; }
    sd[t] = s;
    __syncthreads();
    for (int d = 1; d < 256; d <<= 1) {
        int v = (t >= d) ? sd[t - d] : 0;
        __syncthreads();
        sd[t] += v;
        __syncthreads();
    }
    int acc = sd[t] - s; // exclusive
#pragma unroll
    for (int q = 0; q < 32; q++) { col_off[base_i + q] = acc; cursor[base_i + q] = acc; acc += loc[q]; }
    if (t == 255) col_off[NN] = acc;
}

__global__ __launch_bounds__(256) void k_fill(const int* __restrict__ ei, int* __restrict__ cursor,
                                              int* __restrict__ csr_row, int* __restrict__ csr_eid) {
    int e = blockIdx.x * 256 + threadIdx.x;
    int r = ei[e], c = ei[NE + e];
    int pos = atomicAdd(&cursor[c], 1);
    csr_row[pos] = r;
    csr_eid[pos] = e;
}

// GAT aggregate + bias + ELU + LayerNorm -> h1
__global__ __launch_bounds__(256) void k_gat(const int* __restrict__ col_off, const int* __restrict__ csr_row,
                                             const int* __restrict__ csr_eid,
                                             const float* __restrict__ alpha, const float* __restrict__ aeloop,
                                             const float* __restrict__ a_src, const float* __restrict__ a_dst,
                                             const float* __restrict__ xs, const float* __restrict__ gat_bias,
                                             const float* __restrict__ g, const float* __restrict__ b,
                                             float* __restrict__ h1) {
    int i = blockIdx.x, t = threadIdx.x, h = t >> 6, lane = t & 63;
    int beg = col_off[i], end = col_off[i + 1];
    __shared__ float m_s[4], s_s[4], red[8];
    float sl = a_src[i * 4 + h] + a_dst[i * 4 + h] + aeloop[h];
    sl = sl > 0.f ? sl : 0.2f * sl;
    float mx = sl;
    for (int p = beg + lane; p < end; p += 64) mx = fmaxf(mx, alpha[(size_t)csr_eid[p] * 4 + h]);
    mx = wave_max(mx);
    float ss = (lane == 0) ? expf(sl - mx) : 0.f;
    for (int p = beg + lane; p < end; p += 64) ss += expf(alpha[(size_t)csr_eid[p] * 4 + h] - mx);
    ss = wave_sum(ss);
    if (lane == 0) { m_s[h] = mx; s_s[h] = ss; }
    __syncthreads();
    float minv = m_s[h];
    float sinv = 1.f / (s_s[h] + 1e-16f);
    float acc = expf(sl - minv) * sinv * xs[(size_t)i * 256 + t];
    for (int p = beg; p < end; ++p) {
        int e = csr_eid[p], r = csr_row[p];
        float w = expf(alpha[(size_t)e * 4 + h] - minv) * sinv;
        acc = fmaf(w, xs[(size_t)r * 256 + t], acc);
    }
    float v = eluf(acc + gat_bias[t]);
    float s1 = wave_sum(v), s2 = wave_sum(v * v);
    if (lane == 0) { red[h] = s1; red[4 + h] = s2; }
    __syncthreads();
    float mu = (red[0] + red[1] + red[2] + red[3]) * (1.f / 256.f);
    float m2 = (red[4] + red[5] + red[6] + red[7]) * (1.f / 256.f);
    float var = m2 - mu * mu;
    float rs = rsqrtf(var + 1e-5f);
    h1[(size_t)i * 256 + t] = (v - mu) * rs * g[t] + b[t];
}

// A = h1 @ W1[:256] + b1 ; B = h1 @ W1[256:]
__global__ __launch_bounds__(256) void k_AB(const float* __restrict__ h1, const float* __restrict__ w1,
                                            const float* __restrict__ b1, float* __restrict__ A, float* __restrict__ B) {
    __shared__ float hl[256];
    int i = blockIdx.x, t = threadIdx.x;
    hl[t] = h1[(size_t)i * 256 + t];
    __syncthreads();
    float a = b1[t], bb = 0.f;
#pragma unroll 4
    for (int k = 0; k < 256; k++) {
        float hv = hl[k];
        a = fmaf(hv, w1[k * 256 + t], a);
        bb = fmaf(hv, w1[(256 + k) * 256 + t], bb);
    }
    A[(size_t)i * 256 + t] = a;
    B[(size_t)i * 256 + t] = bb;
}

// per-edge regularizer: prob = sigmoid(elu(A[r]+B[c]) . w2 + b2); scatter to adj + probE
__global__ __launch_bounds__(256) void k_reg(const int* __restrict__ ei, const float* __restrict__ A,
                                             const float* __restrict__ B, const float* __restrict__ w2,
                                             const float* __restrict__ b2, float* __restrict__ probE,
                                             float* __restrict__ adj) {
    int t = threadIdx.x, lane = t & 63;
    int e = blockIdx.x * 4 + (t >> 6);
    int r = ei[e], c = ei[NE + e];
    const float4* A4 = (const float4*)(A + (size_t)r * 256);
    const float4* B4 = (const float4*)(B + (size_t)c * 256);
    float4 av = A4[lane], bv = B4[lane];
    float4 w4 = ((const float4*)w2)[lane];
    float v0 = eluf(av.x + bv.x), v1 = eluf(av.y + bv.y), v2 = eluf(av.z + bv.z), v3 = eluf(av.w + bv.w);
    float s = fmaf(v0, w4.x, fmaf(v1, w4.y, fmaf(v2, w4.z, v3 * w4.w)));
    s = wave_sum(s);
    if (lane == 0) {
        float p = sigmf(s + b2[0]);
        probE[e] = p;
        adj[(size_t)r * NN + c] = p;
    }
}

__global__ __launch_bounds__(256) void k_diag(float* adj) {
    int i = blockIdx.x * blockDim.x + threadIdx.x;
    if (i < NN) adj[(size_t)i * NN + i] = 1.f;
}

__global__ __launch_bounds__(256) void k_coef(const int* __restrict__ ei, const float* __restrict__ probE,
                                              const float* __restrict__ dinv, const float* __restrict__ conf1,
                                              const float* __restrict__ conf2, float* __restrict__ coef1,
                                              float* __restrict__ coef2) {
    int e = blockIdx.x * 256 + threadIdx.x;
    int r = ei[e], c = ei[NE + e];
    float adjv = (r == c) ? 1.f : probE[e];
    float base = dinv[r] * dinv[c] * 0.5f;
    coef1[e] = base * (conf1[e] + adjv);
    coef2[e] = base * (conf2[e] + adjv);
}

// gcn1: agg = sum coef1*h1[row] -> @ g1_lin + b -> ELU -> LN(64) -> h2
__global__ __launch_bounds__(256) void k_gcn1(const int* __restrict__ col_off, const int* __restrict__ csr_row,
                                              const int* __restrict__ csr_eid, const float* __restrict__ coef1,
                                              const float* __restrict__ h1, const float* __restrict__ W,
                                              const float* __restrict__ bias, const float* __restrict__ g,
                                              const float* __restrict__ bb, float* __restrict__ h2) {
    __shared__ float al[256];
    __shared__ float pl[256];
    int i = blockIdx.x, t = threadIdx.x;
    int beg = col_off[i], end = col_off[i + 1];
    float agg = 0.f;
    for (int p = beg; p < end; ++p)
        agg = fmaf(coef1[csr_eid[p]], h1[(size_t)csr_row[p] * 256 + t], agg);
    al[t] = agg;
    __syncthreads();
    int cc = t & 63, q = t >> 6;
    float part = 0.f;
#pragma unroll 4
    for (int k = q * 64; k < q * 64 + 64; k++) part = fmaf(al[k], W[k * 64 + cc], part);
    pl[t] = part;
    __syncthreads();
    if (t < 64) {
        float y = pl[t] + pl[t + 64] + pl[t + 128] + pl[t + 192] + bias[t];
        y = eluf(y);
        float s1 = wave_sum(y), s2 = wave_sum(y * y);
        float mu = s1 * (1.f / 64.f);
        float var = s2 * (1.f / 64.f) - mu * mu;
        h2[(size_t)i * 64 + t] = (y - mu) * rsqrtf(var + 1e-5f) * g[t] + bb[t];
    }
}

// gcn2 + classifier -> logits
__global__ __launch_bounds__(256) void k_gcn2(const int* __restrict__ col_off, const int* __restrict__ csr_row,
                                              const int* __restrict__ csr_eid, const float* __restrict__ coef2,
                                              const float* __restrict__ h2, const float* __restrict__ g2w,
                                              const float* __restrict__ g2b, const float* __restrict__ cw1,
                                              const float* __restrict__ cb1, const float* __restrict__ cw2,
                                              const float* __restrict__ cb2, float* __restrict__ out) {
    __shared__ float zl[4][64];
    __shared__ float ul[4][64];
    __shared__ float tl[4][64];
    int t = threadIdx.x, w = t >> 6, lane = t & 63;
    int i = blockIdx.x * 4 + w;
    int beg = col_off[i], end = col_off[i + 1];
    float z = 0.f;
    for (int p = beg; p < end; ++p)
        z = fmaf(coef2[csr_eid[p]], h2[(size_t)csr_row[p] * 64 + lane], z);
    zl[w][lane] = z;
    __syncthreads();
    float u = g2b[lane];
#pragma unroll 4
    for (int k = 0; k < 64; k++) u = fmaf(zl[w][k], g2w[k * 64 + lane], u);
    ul[w][lane] = u;
    __syncthreads();
    float t1 = cb1[lane];
#pragma unroll 4
    for (int k = 0; k < 64; k++) t1 = fmaf(ul[w][k], cw1[k * 64 + lane], t1);
    t1 = eluf(t1);
    tl[w][lane] = t1;
    __syncthreads();
    if (lane < 8) {
        float o = cb2[lane];
#pragma unroll 4
        for (int k = 0; k < 64; k++) o = fmaf(tl[w][k], cw2[k * 8 + lane], o);
        out[(size_t)i * 8 + lane] = o;
    }
}

// ---------------- launch ----------------
extern "C" void kernel_launch(void* const* d_in, const int* in_sizes, int n_in,
                              void* d_out, int out_size, void* d_ws, size_t ws_size,
                              hipStream_t stream) {
    const float* x           = (const float*)d_in[0];
    const float* edge_attr   = (const float*)d_in[1];
    const float* gat_lin_w   = (const float*)d_in[2];
    const float* gat_lin_edge_w = (const float*)d_in[3];
    const float* att_src     = (const float*)d_in[4];
    const float* att_dst     = (const float*)d_in[5];
    const float* att_edge    = (const float*)d_in[6];
    const float* gat_bias    = (const float*)d_in[7];
    const float* norm1_g     = (const float*)d_in[8];
    const float* norm1_b     = (const float*)d_in[9];
    const float* reg_w1      = (const float*)d_in[10];
    const float* reg_b1      = (const float*)d_in[11];
    const float* reg_w2      = (const float*)d_in[12];
    const float* reg_b2      = (const float*)d_in[13];
    const float* g1_lin_w    = (const float*)d_in[14];
    const float* g1_lin_b    = (const float*)d_in[15];
    const float* g1_conf_w   = (const float*)d_in[16];
    const float* g1_conf_b   = (const float*)d_in[17];
    const float* norm2_g     = (const float*)d_in[18];
    const float* norm2_b     = (const float*)d_in[19];
    const float* g2_lin_w    = (const float*)d_in[20];
    const float* g2_lin_b    = (const float*)d_in[21];
    const float* g2_conf_w   = (const float*)d_in[22];
    const float* g2_conf_b   = (const float*)d_in[23];
    const float* cls_w1      = (const float*)d_in[24];
    const float* cls_b1      = (const float*)d_in[25];
    const float* cls_w2      = (const float*)d_in[26];
    const float* cls_b2      = (const float*)d_in[27];
    const int*   edge_index  = (const int*)d_in[28];

    float* out = (float*)d_out;
    float* adj = out + (size_t)NN * NCLS;

    float* wsf   = (float*)d_ws;
    float* xs    = wsf + OFF_XS;
    float* a_src = wsf + OFF_ASRC;
    float* a_dst = wsf + OFF_ADST;
    float* alpha = wsf + OFF_ALPHA;
    float* conf1 = wsf + OFF_CONF1;
    float* conf2 = wsf + OFF_CONF2;
    float* probE = wsf + OFF_PROBE;
    float* coef1 = wsf + OFF_COEF1;
    float* coef2 = wsf + OFF_COEF2;
    float* h1    = wsf + OFF_H1;
    float* A     = wsf + OFF_A;
    float* B     = wsf + OFF_B;
    float* h2    = wsf + OFF_H2;
    float* dinv  = wsf + OFF_DINV;
    float* sum_ea= wsf + OFF_SUMEA;
    float* M     = wsf + OFF_M;
    float* aeloop= wsf + OFF_AELOOP;
    int* ib      = (int*)(wsf + OFF_INT);
    int* deg_col = ib + IOFF_DEGC;
    int* deg_row = ib + IOFF_DEGR;
    int* col_off = ib + IOFF_COLOFF;
    int* cursor  = ib + IOFF_CURSOR;
    int* csr_row = ib + IOFF_CSRROW;
    int* csr_eid = ib + IOFF_CSREID;

    // 1. zero adj (256 MB) via memset engine + small counters
    hipMemsetAsync(adj, 0, (size_t)NN * NN * sizeof(float), stream);
    kz_small<<<(NN + 255) / 256, 256, 0, stream>>>(deg_col, deg_row, sum_ea);
    // 2. tiny precompute M[3][4]
    k_M<<<1, 64, 0, stream>>>(gat_lin_edge_w, att_edge, M);
    // 3. node transform xs, attention src/dst logits
    k_node<<<NN, 256, 0, stream>>>(x, gat_lin_w, att_src, att_dst, xs, a_src, a_dst);
    // 4. per-edge: alpha logits, conf sigmoids, degree counts, edge_attr sums
    k_edge<<<NE / 256, 256, 0, stream>>>(edge_index, edge_attr, M, a_src, a_dst,
                                         g1_conf_w, g1_conf_b, g2_conf_w, g2_conf_b,
                                         alpha, conf1, conf2, deg_col, deg_row, sum_ea);
    // 5. self-loop logit constant, dinv
    k_loop<<<1, 64, 0, stream>>>(sum_ea, M, aeloop);
    k_dinv<<<(NN + 255) / 256, 256, 0, stream>>>(deg_row, dinv);
    // 6. CSR build
    k_scan<<<1, 256, 0, stream>>>(deg_col, col_off, cursor);
    k_fill<<<NE / 256, 256, 0, stream>>>(edge_index, cursor, csr_row, csr_eid);
    // 7. GAT aggregate + ELU + LN -> h1
    k_gat<<<NN, 256, 0, stream>>>(col_off, csr_row, csr_eid, alpha, aeloop, a_src, a_dst,
                                  xs, gat_bias, norm1_g, norm1_b, h1);
    // 8. regularizer factored GEMMs
    k_AB<<<NN, 256, 0, stream>>>(h1, reg_w1, reg_b1, A, B);
    // 9. per-edge prob + adj scatter
    k_reg<<<NE / 4, 256, 0, stream>>>(edge_index, A, B, reg_w2, reg_b2, probE, adj);
    k_diag<<<(NN + 255) / 256, 256, 0, stream>>>(adj);
    // 10. per-edge gcn coefficients
    k_coef<<<NE / 256, 256, 0, stream>>>(edge_index, probE, dinv, conf1, conf2, coef1, coef2);
    // 11. gcn1 -> h2
    k_gcn1<<<NN, 256, 0, stream>>>(col_off, csr_row, csr_eid, coef1, h1,
                                   g1_lin_w, g1_lin_b, norm2_g, norm2_b, h2);
    // 12. gcn2 + classifier -> logits
    k_gcn2<<<NN / 4, 256, 0, stream>>>(col_off, csr_row, csr_eid, coef2, h2,
                                       g2_lin_w, g2_lin_b, cls_w1, cls_b1, cls_w2, cls_b2, out);
    (void)in_sizes; (void)n_in; (void)out_size; (void)ws_size;
}

// Round 3
// 862.496 us; speedup vs baseline: 1.1459x; 1.1459x over previous
//
#include <hip/hip_runtime.h>
#include <math.h>

#define NN 8192
#define NE 262144
#define FIN 128
#define HC 256
#define CC 64
#define NCLS 8
#define NDNT 16   // nodes per block in k_node
#define ABNT 16   // nodes per block in k_AB

// ---------------- ws layout (floats) ----------------
constexpr size_t OFF_XS    = 0;                              // N*256
constexpr size_t OFF_ASRC  = OFF_XS + (size_t)NN * 256;      // N*4
constexpr size_t OFF_ADST  = OFF_ASRC + (size_t)NN * 4;      // N*4
constexpr size_t OFF_ALPHA = OFF_ADST + (size_t)NN * 4;      // E*4
constexpr size_t OFF_CONF1 = OFF_ALPHA + (size_t)NE * 4;     // E
constexpr size_t OFF_CONF2 = OFF_CONF1 + (size_t)NE;         // E
constexpr size_t OFF_COEF1 = OFF_CONF2 + (size_t)NE;         // E
constexpr size_t OFF_COEF2 = OFF_COEF1 + (size_t)NE;         // E
constexpr size_t OFF_H1    = OFF_COEF2 + (size_t)NE;         // N*256
constexpr size_t OFF_A     = OFF_H1 + (size_t)NN * 256;      // N*256
constexpr size_t OFF_B     = OFF_A + (size_t)NN * 256;       // N*256
constexpr size_t OFF_H2    = OFF_B + (size_t)NN * 256;       // N*64
constexpr size_t OFF_DINV  = OFF_H2 + (size_t)NN * 64;       // N
constexpr size_t OFF_SUMEA = OFF_DINV + (size_t)NN;          // 4 (3 used)
constexpr size_t OFF_M     = OFF_SUMEA + 4;                  // 12
constexpr size_t OFF_AELOOP= OFF_M + 12;                     // 4
constexpr size_t OFF_INT   = OFF_AELOOP + 4;                 // ints from here
constexpr size_t IOFF_DEGC   = 0;                 // NN
constexpr size_t IOFF_DEGR   = IOFF_DEGC + NN;    // NN
constexpr size_t IOFF_COLOFF = IOFF_DEGR + NN;    // NN+1
constexpr size_t IOFF_CURSOR = IOFF_COLOFF + NN + 1; // NN
constexpr size_t IOFF_CSRROW = IOFF_CURSOR + NN;  // NE
constexpr size_t IOFF_CSREID = IOFF_CSRROW + NE;  // NE

// ---------------- helpers ----------------
__device__ __forceinline__ float wave_sum(float v) {
    for (int o = 32; o; o >>= 1) v += __shfl_xor(v, o);
    return v;
}
__device__ __forceinline__ float wave_max(float v) {
    for (int o = 32; o; o >>= 1) v = fmaxf(v, __shfl_xor(v, o));
    return v;
}
__device__ __forceinline__ float eluf(float v) { return v > 0.f ? v : (expf(v) - 1.f); }
__device__ __forceinline__ float sigmf(float v) { return 1.f / (1.f + expf(-v)); }

// ---------------- kernels ----------------
// zero counters, set adj diag (after memset in stream order), compute M[3][4]
__global__ __launch_bounds__(256) void k_init(int* deg_col, int* deg_row, float* sum_ea,
                                              float* adj, const float* lew,
                                              const float* att_edge, float* M) {
    int i = blockIdx.x * blockDim.x + threadIdx.x;
    deg_col[i] = 0;
    deg_row[i] = 0;
    adj[(size_t)i * NN + i] = 1.f;
    if (i < 3) sum_ea[i] = 0.f;
    if (i < 12) {
        int d = i >> 2, h = i & 3;
        float s = 0.f;
        for (int c = 0; c < 64; c++) s = fmaf(lew[d * 256 + h * 64 + c], att_edge[h * 64 + c], s);
        M[i] = s; // M[d*4+h]
    }
}

// xs = x @ gat_lin_w ; a_src/a_dst per (node, head). Tiled: NDNT nodes/block.
__global__ __launch_bounds__(256) void k_node(const float* __restrict__ x, const float* __restrict__ W,
                                              const float* __restrict__ att_src, const float* __restrict__ att_dst,
                                              float* __restrict__ xs, float* __restrict__ a_src, float* __restrict__ a_dst) {
    __shared__ float xl[NDNT * FIN];
    int b = blockIdx.x, t = threadIdx.x;
    size_t base = (size_t)b * NDNT;
#pragma unroll
    for (int q = 0; q < NDNT * FIN / 256; ++q) {
        int idx = q * 256 + t;
        xl[idx] = x[base * FIN + idx];
    }
    __syncthreads();
    float acc[NDNT];
#pragma unroll
    for (int n = 0; n < NDNT; ++n) acc[n] = 0.f;
    for (int k = 0; k < FIN; ++k) {
        float wv = W[k * 256 + t];
#pragma unroll
        for (int n = 0; n < NDNT; ++n) acc[n] = fmaf(xl[n * FIN + k], wv, acc[n]);
    }
    float as = att_src[t], ad = att_dst[t];
#pragma unroll
    for (int n = 0; n < NDNT; ++n) {
        xs[(base + n) * 256 + t] = acc[n];
        float ps = wave_sum(acc[n] * as);
        float pd = wave_sum(acc[n] * ad);
        if ((t & 63) == 0) {
            a_src[(base + n) * 4 + (t >> 6)] = ps;
            a_dst[(base + n) * 4 + (t >> 6)] = pd;
        }
    }
}

__global__ __launch_bounds__(256) void k_edge(const int* __restrict__ ei, const float* __restrict__ eattr,
                                              const float* __restrict__ M,
                                              const float* __restrict__ a_src, const float* __restrict__ a_dst,
                                              const float* __restrict__ c1w, const float* __restrict__ c1b,
                                              const float* __restrict__ c2w, const float* __restrict__ c2b,
                                              float* __restrict__ alpha, float* __restrict__ conf1, float* __restrict__ conf2,
                                              int* __restrict__ deg_col, int* __restrict__ deg_row, float* __restrict__ sum_ea) {
    int e = blockIdx.x * 256 + threadIdx.x;
    int r = ei[e], c = ei[NE + e];
    float ea0 = eattr[e * 3 + 0], ea1 = eattr[e * 3 + 1], ea2 = eattr[e * 3 + 2];
#pragma unroll
    for (int h = 0; h < 4; h++) {
        float ae = fmaf(ea0, M[0 * 4 + h], fmaf(ea1, M[1 * 4 + h], ea2 * M[2 * 4 + h]));
        float v = a_src[r * 4 + h] + a_dst[c * 4 + h] + ae;
        alpha[(size_t)e * 4 + h] = v > 0.f ? v : 0.2f * v;
    }
    conf1[e] = sigmf(fmaf(ea0, c1w[0], fmaf(ea1, c1w[1], fmaf(ea2, c1w[2], c1b[0]))));
    conf2[e] = sigmf(fmaf(ea0, c2w[0], fmaf(ea1, c2w[1], fmaf(ea2, c2w[2], c2b[0]))));
    atomicAdd(&deg_col[c], 1);
    atomicAdd(&deg_row[r], 1);
    float s0 = wave_sum(ea0), s1 = wave_sum(ea1), s2 = wave_sum(ea2);
    if ((threadIdx.x & 63) == 0) {
        atomicAdd(&sum_ea[0], s0); atomicAdd(&sum_ea[1], s1); atomicAdd(&sum_ea[2], s2);
    }
}

// self-loop logit constant + dinv
__global__ __launch_bounds__(256) void k_loopdinv(const float* sum_ea, const float* M, float* aeloop,
                                                  const int* deg_row, float* dinv) {
    int i = blockIdx.x * blockDim.x + threadIdx.x;
    if (i < 4) {
        float m0 = sum_ea[0] * (1.f / NE), m1 = sum_ea[1] * (1.f / NE), m2 = sum_ea[2] * (1.f / NE);
        aeloop[i] = fmaf(m0, M[0 * 4 + i], fmaf(m1, M[1 * 4 + i], m2 * M[2 * 4 + i]));
    }
    int d = deg_row[i];
    dinv[i] = d > 0 ? rsqrtf((float)d) : 0.f;
}

__global__ __launch_bounds__(256) void k_scan(const int* __restrict__ deg_col, int* __restrict__ col_off, int* __restrict__ cursor) {
    __shared__ int sd[256];
    int t = threadIdx.x;
    int base_i = t * 32;
    int loc[32];
    int s = 0;
#pragma unroll
    for (int q = 0; q < 32; q++) { loc[q] = deg_col[base_i + q]; s += loc[q]; }
    sd[t] = s;
    __syncthreads();
    for (int d = 1; d < 256; d <<= 1) {
        int v = (t >= d) ? sd[t - d] : 0;
        __syncthreads();
        sd[t] += v;
        __syncthreads();
    }
    int acc = sd[t] - s; // exclusive
#pragma unroll
    for (int q = 0; q < 32; q++) { col_off[base_i + q] = acc; cursor[base_i + q] = acc; acc += loc[q]; }
    if (t == 255) col_off[NN] = acc;
}

__global__ __launch_bounds__(256) void k_fill(const int* __restrict__ ei, int* __restrict__ cursor,
                                              int* __restrict__ csr_row, int* __restrict__ csr_eid) {
    int e = blockIdx.x * 256 + threadIdx.x;
    int r = ei[e], c = ei[NE + e];
    int pos = atomicAdd(&cursor[c], 1);
    csr_row[pos] = r;
    csr_eid[pos] = e;
}

// GAT aggregate + bias + ELU + LayerNorm -> h1 (weights precomputed per 64-edge chunk)
__global__ __launch_bounds__(256) void k_gat(const int* __restrict__ col_off, const int* __restrict__ csr_row,
                                             const int* __restrict__ csr_eid,
                                             const float* __restrict__ alpha, const float* __restrict__ aeloop,
                                             const float* __restrict__ a_src, const float* __restrict__ a_dst,
                                             const float* __restrict__ xs, const float* __restrict__ gat_bias,
                                             const float* __restrict__ g, const float* __restrict__ b,
                                             float* __restrict__ h1) {
    int i = blockIdx.x, t = threadIdx.x, h = t >> 6, lane = t & 63;
    int beg = col_off[i], end = col_off[i + 1];
    __shared__ float m_s[4], s_s[4], red[8];
    __shared__ float wl[64][5];   // pad 5 to avoid bank conflicts on write
    float sl = a_src[i * 4 + h] + a_dst[i * 4 + h] + aeloop[h];
    sl = sl > 0.f ? sl : 0.2f * sl;
    float mx = sl;
    for (int p = beg + lane; p < end; p += 64) mx = fmaxf(mx, alpha[(size_t)csr_eid[p] * 4 + h]);
    mx = wave_max(mx);
    float ss = (lane == 0) ? expf(sl - mx) : 0.f;
    for (int p = beg + lane; p < end; p += 64) ss += expf(alpha[(size_t)csr_eid[p] * 4 + h] - mx);
    ss = wave_sum(ss);
    if (lane == 0) { m_s[h] = mx; s_s[h] = ss; }
    __syncthreads();
    float minv = m_s[h];
    float sinv = 1.f / (s_s[h] + 1e-16f);
    float acc = expf(sl - minv) * sinv * xs[(size_t)i * 256 + t];
    for (int cb = beg; cb < end; cb += 64) {
        int ce = min(cb + 64, end);
        int p = cb + lane;
        if (p < ce) wl[lane][h] = expf(alpha[(size_t)csr_eid[p] * 4 + h] - minv) * sinv;
        __syncthreads();
        int n = ce - cb;
        for (int q = 0; q < n; ++q)
            acc = fmaf(wl[q][h], xs[(size_t)csr_row[cb + q] * 256 + t], acc);
        __syncthreads();
    }
    float v = eluf(acc + gat_bias[t]);
    float s1 = wave_sum(v), s2 = wave_sum(v * v);
    if (lane == 0) { red[h] = s1; red[4 + h] = s2; }
    __syncthreads();
    float mu = (red[0] + red[1] + red[2] + red[3]) * (1.f / 256.f);
    float m2 = (red[4] + red[5] + red[6] + red[7]) * (1.f / 256.f);
    float var = m2 - mu * mu;
    float rs = rsqrtf(var + 1e-5f);
    h1[(size_t)i * 256 + t] = (v - mu) * rs * g[t] + b[t];
}

// A = h1 @ W1[:256] + b1 ; B = h1 @ W1[256:]  (tiled: ABNT nodes/block)
__global__ __launch_bounds__(256) void k_AB(const float* __restrict__ h1, const float* __restrict__ w1,
                                            const float* __restrict__ b1, float* __restrict__ A, float* __restrict__ B) {
    __shared__ float hl[ABNT * 256];
    int bk = blockIdx.x, t = threadIdx.x;
    size_t base = (size_t)bk * ABNT;
#pragma unroll
    for (int n = 0; n < ABNT; ++n) hl[n * 256 + t] = h1[(base + n) * 256 + t];
    __syncthreads();
    float accA[ABNT], accB[ABNT];
    float bv = b1[t];
#pragma unroll
    for (int n = 0; n < ABNT; ++n) { accA[n] = bv; accB[n] = 0.f; }
    for (int k = 0; k < 256; ++k) {
        float wa = w1[k * 256 + t];
        float wb = w1[(256 + k) * 256 + t];
#pragma unroll
        for (int n = 0; n < ABNT; ++n) {
            float hv = hl[n * 256 + k];
            accA[n] = fmaf(hv, wa, accA[n]);
            accB[n] = fmaf(hv, wb, accB[n]);
        }
    }
#pragma unroll
    for (int n = 0; n < ABNT; ++n) {
        A[(base + n) * 256 + t] = accA[n];
        B[(base + n) * 256 + t] = accB[n];
    }
}

// per-edge regularizer + gcn coefficients fused:
// prob = sigmoid(elu(A[r]+B[c]).w2 + b2); adj scatter (skip diag); coef1/2
__global__ __launch_bounds__(256) void k_regc(const int* __restrict__ ei, const float* __restrict__ A,
                                              const float* __restrict__ B, const float* __restrict__ w2,
                                              const float* __restrict__ b2, const float* __restrict__ dinv,
                                              const float* __restrict__ conf1, const float* __restrict__ conf2,
                                              float* __restrict__ adj, float* __restrict__ coef1,
                                              float* __restrict__ coef2) {
    int t = threadIdx.x, lane = t & 63;
    int e = blockIdx.x * 4 + (t >> 6);
    int r = ei[e], c = ei[NE + e];
    const float4* A4 = (const float4*)(A + (size_t)r * 256);
    const float4* B4 = (const float4*)(B + (size_t)c * 256);
    float4 av = A4[lane], bv = B4[lane];
    float4 w4 = ((const float4*)w2)[lane];
    float v0 = eluf(av.x + bv.x), v1 = eluf(av.y + bv.y), v2 = eluf(av.z + bv.z), v3 = eluf(av.w + bv.w);
    float s = fmaf(v0, w4.x, fmaf(v1, w4.y, fmaf(v2, w4.z, v3 * w4.w)));
    s = wave_sum(s);
    if (lane == 0) {
        float p = sigmf(s + b2[0]);
        float adjv;
        if (r != c) { adj[(size_t)r * NN + c] = p; adjv = p; }
        else adjv = 1.f;
        float base = dinv[r] * dinv[c] * 0.5f;
        coef1[e] = base * (conf1[e] + adjv);
        coef2[e] = base * (conf2[e] + adjv);
    }
}

// gcn1: agg = sum coef1*h1[row] -> @ g1_lin + b -> ELU -> LN(64) -> h2
__global__ __launch_bounds__(256) void k_gcn1(const int* __restrict__ col_off, const int* __restrict__ csr_row,
                                              const int* __restrict__ csr_eid, const float* __restrict__ coef1,
                                              const float* __restrict__ h1, const float* __restrict__ W,
                                              const float* __restrict__ bias, const float* __restrict__ g,
                                              const float* __restrict__ bb, float* __restrict__ h2) {
    __shared__ float al[256];
    __shared__ float pl[256];
    int i = blockIdx.x, t = threadIdx.x;
    int beg = col_off[i], end = col_off[i + 1];
    float agg = 0.f;
    for (int p = beg; p < end; ++p)
        agg = fmaf(coef1[csr_eid[p]], h1[(size_t)csr_row[p] * 256 + t], agg);
    al[t] = agg;
    __syncthreads();
    int cc = t & 63, q = t >> 6;
    float part = 0.f;
#pragma unroll 4
    for (int k = q * 64; k < q * 64 + 64; k++) part = fmaf(al[k], W[k * 64 + cc], part);
    pl[t] = part;
    __syncthreads();
    if (t < 64) {
        float y = pl[t] + pl[t + 64] + pl[t + 128] + pl[t + 192] + bias[t];
        y = eluf(y);
        float s1 = wave_sum(y), s2 = wave_sum(y * y);
        float mu = s1 * (1.f / 64.f);
        float var = s2 * (1.f / 64.f) - mu * mu;
        h2[(size_t)i * 64 + t] = (y - mu) * rsqrtf(var + 1e-5f) * g[t] + bb[t];
    }
}

// gcn2 + classifier -> logits
__global__ __launch_bounds__(256) void k_gcn2(const int* __restrict__ col_off, const int* __restrict__ csr_row,
                                              const int* __restrict__ csr_eid, const float* __restrict__ coef2,
                                              const float* __restrict__ h2, const float* __restrict__ g2w,
                                              const float* __restrict__ g2b, const float* __restrict__ cw1,
                                              const float* __restrict__ cb1, const float* __restrict__ cw2,
                                              const float* __restrict__ cb2, float* __restrict__ out) {
    __shared__ float zl[4][64];
    __shared__ float ul[4][64];
    __shared__ float tl[4][64];
    int t = threadIdx.x, w = t >> 6, lane = t & 63;
    int i = blockIdx.x * 4 + w;
    int beg = col_off[i], end = col_off[i + 1];
    float z = 0.f;
    for (int p = beg; p < end; ++p)
        z = fmaf(coef2[csr_eid[p]], h2[(size_t)csr_row[p] * 64 + lane], z);
    zl[w][lane] = z;
    __syncthreads();
    float u = g2b[lane];
#pragma unroll 4
    for (int k = 0; k < 64; k++) u = fmaf(zl[w][k], g2w[k * 64 + lane], u);
    ul[w][lane] = u;
    __syncthreads();
    float t1 = cb1[lane];
#pragma unroll 4
    for (int k = 0; k < 64; k++) t1 = fmaf(ul[w][k], cw1[k * 64 + lane], t1);
    t1 = eluf(t1);
    tl[w][lane] = t1;
    __syncthreads();
    if (lane < 8) {
        float o = cb2[lane];
#pragma unroll 4
        for (int k = 0; k < 64; k++) o = fmaf(tl[w][k], cw2[k * 8 + lane], o);
        out[(size_t)i * 8 + lane] = o;
    }
}

// ---------------- launch ----------------
extern "C" void kernel_launch(void* const* d_in, const int* in_sizes, int n_in,
                              void* d_out, int out_size, void* d_ws, size_t ws_size,
                              hipStream_t stream) {
    const float* x           = (const float*)d_in[0];
    const float* edge_attr   = (const float*)d_in[1];
    const float* gat_lin_w   = (const float*)d_in[2];
    const float* gat_lin_edge_w = (const float*)d_in[3];
    const float* att_src     = (const float*)d_in[4];
    const float* att_dst     = (const float*)d_in[5];
    const float* att_edge    = (const float*)d_in[6];
    const float* gat_bias    = (const float*)d_in[7];
    const float* norm1_g     = (const float*)d_in[8];
    const float* norm1_b     = (const float*)d_in[9];
    const float* reg_w1      = (const float*)d_in[10];
    const float* reg_b1      = (const float*)d_in[11];
    const float* reg_w2      = (const float*)d_in[12];
    const float* reg_b2      = (const float*)d_in[13];
    const float* g1_lin_w    = (const float*)d_in[14];
    const float* g1_lin_b    = (const float*)d_in[15];
    const float* g1_conf_w   = (const float*)d_in[16];
    const float* g1_conf_b   = (const float*)d_in[17];
    const float* norm2_g     = (const float*)d_in[18];
    const float* norm2_b     = (const float*)d_in[19];
    const float* g2_lin_w    = (const float*)d_in[20];
    const float* g2_lin_b    = (const float*)d_in[21];
    const float* g2_conf_w   = (const float*)d_in[22];
    const float* g2_conf_b   = (const float*)d_in[23];
    const float* cls_w1      = (const float*)d_in[24];
    const float* cls_b1      = (const float*)d_in[25];
    const float* cls_w2      = (const float*)d_in[26];
    const float* cls_b2      = (const float*)d_in[27];
    const int*   edge_index  = (const int*)d_in[28];

    float* out = (float*)d_out;
    float* adj = out + (size_t)NN * NCLS;

    float* wsf   = (float*)d_ws;
    float* xs    = wsf + OFF_XS;
    float* a_src = wsf + OFF_ASRC;
    float* a_dst = wsf + OFF_ADST;
    float* alpha = wsf + OFF_ALPHA;
    float* conf1 = wsf + OFF_CONF1;
    float* conf2 = wsf + OFF_CONF2;
    float* coef1 = wsf + OFF_COEF1;
    float* coef2 = wsf + OFF_COEF2;
    float* h1    = wsf + OFF_H1;
    float* A     = wsf + OFF_A;
    float* B     = wsf + OFF_B;
    float* h2    = wsf + OFF_H2;
    float* dinv  = wsf + OFF_DINV;
    float* sum_ea= wsf + OFF_SUMEA;
    float* M     = wsf + OFF_M;
    float* aeloop= wsf + OFF_AELOOP;
    int* ib      = (int*)(wsf + OFF_INT);
    int* deg_col = ib + IOFF_DEGC;
    int* deg_row = ib + IOFF_DEGR;
    int* col_off = ib + IOFF_COLOFF;
    int* cursor  = ib + IOFF_CURSOR;
    int* csr_row = ib + IOFF_CSRROW;
    int* csr_eid = ib + IOFF_CSREID;

    // 1. zero adj (268 MB) via copy/fill engine; then init (diag, counters, M)
    hipMemsetAsync(adj, 0, (size_t)NN * NN * sizeof(float), stream);
    k_init<<<NN / 256, 256, 0, stream>>>(deg_col, deg_row, sum_ea, adj,
                                         gat_lin_edge_w, att_edge, M);
    // 2. node transform xs (tiled), attention src/dst logits
    k_node<<<NN / NDNT, 256, 0, stream>>>(x, gat_lin_w, att_src, att_dst, xs, a_src, a_dst);
    // 3. per-edge: alpha logits, conf sigmoids, degree counts, edge_attr sums
    k_edge<<<NE / 256, 256, 0, stream>>>(edge_index, edge_attr, M, a_src, a_dst,
                                         g1_conf_w, g1_conf_b, g2_conf_w, g2_conf_b,
                                         alpha, conf1, conf2, deg_col, deg_row, sum_ea);
    // 4. self-loop logit constant + dinv
    k_loopdinv<<<NN / 256, 256, 0, stream>>>(sum_ea, M, aeloop, deg_row, dinv);
    // 5. CSR build
    k_scan<<<1, 256, 0, stream>>>(deg_col, col_off, cursor);
    k_fill<<<NE / 256, 256, 0, stream>>>(edge_index, cursor, csr_row, csr_eid);
    // 6. GAT aggregate + ELU + LN -> h1
    k_gat<<<NN, 256, 0, stream>>>(col_off, csr_row, csr_eid, alpha, aeloop, a_src, a_dst,
                                  xs, gat_bias, norm1_g, norm1_b, h1);
    // 7. regularizer factored GEMMs (tiled)
    k_AB<<<NN / ABNT, 256, 0, stream>>>(h1, reg_w1, reg_b1, A, B);
    // 8. per-edge prob + adj scatter + gcn coefficients (fused)
    k_regc<<<NE / 4, 256, 0, stream>>>(edge_index, A, B, reg_w2, reg_b2, dinv,
                                       conf1, conf2, adj, coef1, coef2);
    // 9. gcn1 -> h2
    k_gcn1<<<NN, 256, 0, stream>>>(col_off, csr_row, csr_eid, coef1, h1,
                                   g1_lin_w, g1_lin_b, norm2_g, norm2_b, h2);
    // 10. gcn2 + classifier -> logits
    k_gcn2<<<NN / 4, 256, 0, stream>>>(col_off, csr_row, csr_eid, coef2, h2,
                                       g2_lin_w, g2_lin_b, cls_w1, cls_b1, cls_w2, cls_b2, out);
    (void)in_sizes; (void)n_in; (void)out_size; (void)ws_size;
}